// Round 1
// baseline (792.496 us; speedup 1.0000x reference)
//
#include <hip/hip_runtime.h>
#include <stdint.h>

#define FP8_MAX 448.0f

typedef float f32x4 __attribute__((ext_vector_type(4)));

// ---------- helpers ----------

// async global->LDS, 16B per lane. LDS dest must be wave-uniform base + lane*16.
__device__ __forceinline__ void async_load16(const void* gptr, void* lptr) {
  __builtin_amdgcn_global_load_lds(
      (const __attribute__((address_space(1))) unsigned int*)(uintptr_t)gptr,
      (__attribute__((address_space(3))) unsigned int*)(unsigned)(uintptr_t)lptr,
      16, 0, 0);
}

// pack 4 fp32 -> 4 fp8 e4m3fn bytes (RNE, OCP on gfx950), byte0 = a
__device__ __forceinline__ unsigned pack4_fp8(float a, float b, float c, float d) {
  int v = __builtin_amdgcn_cvt_pk_fp8_f32(a, b, 0, false);
  v = __builtin_amdgcn_cvt_pk_fp8_f32(c, d, v, true);
  return (unsigned)v;
}

__device__ __forceinline__ float clip_fp8(float q) {
  return fminf(FP8_MAX, fmaxf(-FP8_MAX, q));
}

// ---------- pass 1: amax reduction ----------

__global__ void k_amax(const float4* __restrict__ x, long n4, unsigned* __restrict__ out) {
  float m = 0.f;
  const long stride = (long)gridDim.x * blockDim.x;
  for (long i = (long)blockIdx.x * blockDim.x + threadIdx.x; i < n4; i += stride) {
    float4 v = x[i];
    m = fmaxf(m, fmaxf(fmaxf(fabsf(v.x), fabsf(v.y)), fmaxf(fabsf(v.z), fabsf(v.w))));
  }
#pragma unroll
  for (int off = 32; off > 0; off >>= 1)
    m = fmaxf(m, __shfl_xor(m, off, 64));
  __shared__ float sm[4];
  const int wv = threadIdx.x >> 6;
  if ((threadIdx.x & 63) == 0) sm[wv] = m;
  __syncthreads();
  if (threadIdx.x == 0) {
    m = fmaxf(fmaxf(sm[0], sm[1]), fmaxf(sm[2], sm[3]));
    // all values >= 0: uint bit-pattern order == float order
    atomicMax(out, __float_as_uint(m));
  }
}

// ---------- pass 2: quantize x (divide by scale, clip, RNE->fp8) ----------

__global__ void k_quant_x(const float4* __restrict__ x, uint4* __restrict__ q,
                          const unsigned* __restrict__ amax_bits) {
  const float scale = fmaxf(__uint_as_float(*amax_bits), 1e-12f) / 448.0f;
  const long tid = (long)blockIdx.x * blockDim.x + threadIdx.x;
  float4 v[4];
#pragma unroll
  for (int i = 0; i < 4; i++) v[i] = x[tid * 4 + i];
  uint4 r;
  unsigned* rp = &r.x;
#pragma unroll
  for (int i = 0; i < 4; i++) {
    // true IEEE division to match reference rounding
    float a = clip_fp8(v[i].x / scale);
    float b = clip_fp8(v[i].y / scale);
    float c = clip_fp8(v[i].z / scale);
    float d = clip_fp8(v[i].w / scale);
    rp[i] = pack4_fp8(a, b, c, d);
  }
  q[tid] = r;
}

// ---------- pass 3: quantize weight (values pre-scaled; just RNE->fp8) ----------

__global__ void k_quant_w(const float4* __restrict__ w, uint4* __restrict__ q) {
  const long tid = (long)blockIdx.x * blockDim.x + threadIdx.x;
  float4 v[4];
#pragma unroll
  for (int i = 0; i < 4; i++) v[i] = w[tid * 4 + i];
  uint4 r;
  unsigned* rp = &r.x;
#pragma unroll
  for (int i = 0; i < 4; i++) {
    float a = clip_fp8(v[i].x);
    float b = clip_fp8(v[i].y);
    float c = clip_fp8(v[i].z);
    float d = clip_fp8(v[i].w);
    rp[i] = pack4_fp8(a, b, c, d);
  }
  q[tid] = r;
}

// ---------- pass 4: fp8 GEMM, 128x128 tile, BK=64, 16x16x32 MFMA ----------
// A: qx [M x K] row-major fp8. B: qw [N x K] row-major fp8 (einsum 'bsd,od').
// out[m][n] = (sum_k A[m,k]*B[n,k]) * s_comb + bias[n]

__global__ __launch_bounds__(256) void k_gemm(
    const unsigned char* __restrict__ qa, const unsigned char* __restrict__ qb,
    const unsigned* __restrict__ amax_bits, const float* __restrict__ wscale,
    const float* __restrict__ bias, float* __restrict__ out,
    int M, int N, int K) {
  __shared__ unsigned char lds_a[128 * 64];
  __shared__ unsigned char lds_b[128 * 64];

  const int t = threadIdx.x;
  const int lane = t & 63;
  const int wv = t >> 6;
  const int wm = wv >> 1, wn = wv & 1;      // 2x2 wave grid, 64x64 per wave
  const int lrow = lane & 15, lq = lane >> 4;

  const int bx = blockIdx.x;  // n tile
  const int by = blockIdx.y;  // m tile

  const unsigned char* Ag = qa + (size_t)by * 128 * K;
  const unsigned char* Bg = qb + (size_t)bx * 128 * K;

  // staging: tile is 128 rows x 64 bytes = 8192 B -> 2 rounds of 256 lanes x 16 B
  const int idx0 = t, idx1 = t + 256;
  const size_t a_off0 = (size_t)(idx0 >> 2) * K + (size_t)(idx0 & 3) * 16;
  const size_t a_off1 = (size_t)(idx1 >> 2) * K + (size_t)(idx1 & 3) * 16;

  f32x4 acc[4][4];
#pragma unroll
  for (int i = 0; i < 4; i++)
#pragma unroll
    for (int j = 0; j < 4; j++) acc[i][j] = (f32x4){0.f, 0.f, 0.f, 0.f};

  for (int kt = 0; kt < K; kt += 64) {
    async_load16(Ag + a_off0 + kt, lds_a + idx0 * 16);
    async_load16(Ag + a_off1 + kt, lds_a + idx1 * 16);
    async_load16(Bg + a_off0 + kt, lds_b + idx0 * 16);
    async_load16(Bg + a_off1 + kt, lds_b + idx1 * 16);
    __syncthreads();  // compiler emits vmcnt(0) drain before s_barrier

#pragma unroll
    for (int s = 0; s < 2; s++) {
      long af[4], bf[4];
#pragma unroll
      for (int i = 0; i < 4; i++)
        af[i] = *(const long*)(lds_a + (wm * 64 + i * 16 + lrow) * 64 + s * 32 + lq * 8);
#pragma unroll
      for (int j = 0; j < 4; j++)
        bf[j] = *(const long*)(lds_b + (wn * 64 + j * 16 + lrow) * 64 + s * 32 + lq * 8);
#pragma unroll
      for (int i = 0; i < 4; i++)
#pragma unroll
        for (int j = 0; j < 4; j++)
          acc[i][j] = __builtin_amdgcn_mfma_f32_16x16x32_fp8_fp8(af[i], bf[j], acc[i][j], 0, 0, 0);
    }
    __syncthreads();
  }

  const float s_comb =
      (fmaxf(__uint_as_float(*amax_bits), 1e-12f) / 448.0f) * wscale[0];
  const int m_base = by * 128 + wm * 64;
  const int n_base = bx * 128 + wn * 64;
#pragma unroll
  for (int j = 0; j < 4; j++) {
    const int col = n_base + j * 16 + lrow;
    const float bv = bias[col];
#pragma unroll
    for (int i = 0; i < 4; i++) {
      const int row0 = m_base + i * 16 + lq * 4;
      float* po = out + (size_t)row0 * N + col;
#pragma unroll
      for (int r = 0; r < 4; r++)
        po[(size_t)r * N] = acc[i][j][r] * s_comb + bv;
    }
  }
}

// ---------- launch ----------

extern "C" void kernel_launch(void* const* d_in, const int* in_sizes, int n_in,
                              void* d_out, int out_size, void* d_ws, size_t ws_size,
                              hipStream_t stream) {
  const float* x = (const float*)d_in[0];        // [B,S,K] fp32
  const float* qw = (const float*)d_in[1];       // [N,K] fp32 (pre-scaled fp8 values)
  const float* wscale = (const float*)d_in[2];   // [1] fp32
  const float* bias = (const float*)d_in[3];     // [N] fp32

  const int N = in_sizes[3];
  const int K = in_sizes[1] / N;
  const int M = in_sizes[0] / K;

  const long nx = (long)M * K;
  const long nw = (long)N * K;

  unsigned char* ws = (unsigned char*)d_ws;
  unsigned* amax_bits = (unsigned*)ws;
  unsigned char* qx8 = ws + 256;
  unsigned char* qw8 = qx8 + nx;

  float* out = (float*)d_out;

  hipMemsetAsync(d_ws, 0, 4, stream);
  k_amax<<<2048, 256, 0, stream>>>((const float4*)x, nx / 4, amax_bits);
  k_quant_x<<<(int)(nx / (256 * 16)), 256, 0, stream>>>((const float4*)x, (uint4*)qx8, amax_bits);
  k_quant_w<<<(int)(nw / (256 * 16)), 256, 0, stream>>>((const float4*)qw, (uint4*)qw8);
  dim3 grid(N / 128, M / 128);
  k_gemm<<<grid, 256, 0, stream>>>(qx8, qw8, amax_bits, wscale, bias, out, M, N, K);
}

// Round 2
// 629.139 us; speedup vs baseline: 1.2597x; 1.2597x over previous
//
#include <hip/hip_runtime.h>
#include <stdint.h>

#define FP8_MAX 448.0f

typedef float f32x4 __attribute__((ext_vector_type(4)));

// ---------- helpers ----------

// async global->LDS, 16B per lane. LDS dest must be wave-uniform base + lane*16.
__device__ __forceinline__ void async_load16(const void* gptr, void* lptr) {
  __builtin_amdgcn_global_load_lds(
      (const __attribute__((address_space(1))) unsigned int*)(uintptr_t)gptr,
      (__attribute__((address_space(3))) unsigned int*)(unsigned)(uintptr_t)lptr,
      16, 0, 0);
}

// pack 4 fp32 -> 4 fp8 e4m3fn bytes (RNE, OCP on gfx950), byte0 = a
__device__ __forceinline__ unsigned pack4_fp8(float a, float b, float c, float d) {
  int v = __builtin_amdgcn_cvt_pk_fp8_f32(a, b, 0, false);
  v = __builtin_amdgcn_cvt_pk_fp8_f32(c, d, v, true);
  return (unsigned)v;
}

__device__ __forceinline__ float clip_fp8(float q) {
  return fminf(FP8_MAX, fmaxf(-FP8_MAX, q));
}

// ---------- pass 1: amax reduction ----------

__global__ void k_amax(const float4* __restrict__ x, long n4, unsigned* __restrict__ out) {
  float m = 0.f;
  const long stride = (long)gridDim.x * blockDim.x;
  for (long i = (long)blockIdx.x * blockDim.x + threadIdx.x; i < n4; i += stride) {
    float4 v = x[i];
    m = fmaxf(m, fmaxf(fmaxf(fabsf(v.x), fabsf(v.y)), fmaxf(fabsf(v.z), fabsf(v.w))));
  }
#pragma unroll
  for (int off = 32; off > 0; off >>= 1)
    m = fmaxf(m, __shfl_xor(m, off, 64));
  __shared__ float sm[4];
  const int wv = threadIdx.x >> 6;
  if ((threadIdx.x & 63) == 0) sm[wv] = m;
  __syncthreads();
  if (threadIdx.x == 0) {
    m = fmaxf(fmaxf(sm[0], sm[1]), fmaxf(sm[2], sm[3]));
    // all values >= 0: uint bit-pattern order == float order
    atomicMax(out, __float_as_uint(m));
  }
}

// ---------- pass 2: quantize x (divide by scale, clip, RNE->fp8) ----------

__global__ void k_quant_x(const float4* __restrict__ x, uint4* __restrict__ q,
                          const unsigned* __restrict__ amax_bits) {
  const float scale = fmaxf(__uint_as_float(*amax_bits), 1e-12f) / 448.0f;
  const long tid = (long)blockIdx.x * blockDim.x + threadIdx.x;
  float4 v[4];
#pragma unroll
  for (int i = 0; i < 4; i++) v[i] = x[tid * 4 + i];
  uint4 r;
  unsigned* rp = &r.x;
#pragma unroll
  for (int i = 0; i < 4; i++) {
    // true IEEE division to match reference rounding
    float a = clip_fp8(v[i].x / scale);
    float b = clip_fp8(v[i].y / scale);
    float c = clip_fp8(v[i].z / scale);
    float d = clip_fp8(v[i].w / scale);
    rp[i] = pack4_fp8(a, b, c, d);
  }
  q[tid] = r;
}

// ---------- pass 3: quantize weight (values pre-scaled; just RNE->fp8) ----------

__global__ void k_quant_w(const float4* __restrict__ w, uint4* __restrict__ q) {
  const long tid = (long)blockIdx.x * blockDim.x + threadIdx.x;
  float4 v[4];
#pragma unroll
  for (int i = 0; i < 4; i++) v[i] = w[tid * 4 + i];
  uint4 r;
  unsigned* rp = &r.x;
#pragma unroll
  for (int i = 0; i < 4; i++) {
    float a = clip_fp8(v[i].x);
    float b = clip_fp8(v[i].y);
    float c = clip_fp8(v[i].z);
    float d = clip_fp8(v[i].w);
    rp[i] = pack4_fp8(a, b, c, d);
  }
  q[tid] = r;
}

// ---------- pass 4: fp8 GEMM, 128x128 tile, BK=64, 16x16x32 MFMA ----------
// A: qx [M x K] row-major fp8. B: qw [N x K] row-major fp8 (einsum 'bsd,od').
// out[m][n] = (sum_k A[m,k]*B[n,k]) * s_comb + bias[n]
//
// LDS layout is XOR-swizzled at 16-B granularity: global chunk g of row r
// lives at LDS slot (g ^ (r&3)). The swizzle is applied on the GLOBAL source
// address during global_load_lds staging (lane->LDS mapping stays contiguous
// as the HW requires), and on the LDS address during fragment reads.
// This spreads the b64 fragment reads across all 32 banks (4 lanes/bank-pair
// = the b64 minimum) instead of 8 bank-pairs (8-way conflict).

__global__ __launch_bounds__(256) void k_gemm(
    const unsigned char* __restrict__ qa, const unsigned char* __restrict__ qb,
    const unsigned* __restrict__ amax_bits, const float* __restrict__ wscale,
    const float* __restrict__ bias, float* __restrict__ out,
    int M, int N, int K) {
  __shared__ unsigned char lds_a[128 * 64];
  __shared__ unsigned char lds_b[128 * 64];

  const int t = threadIdx.x;
  const int lane = t & 63;
  const int wv = t >> 6;
  const int wm = wv >> 1, wn = wv & 1;      // 2x2 wave grid, 64x64 per wave
  const int lrow = lane & 15, lq = lane >> 4;

  const int bx = blockIdx.x;  // n tile
  const int by = blockIdx.y;  // m tile

  const unsigned char* Ag = qa + (size_t)by * 128 * K;
  const unsigned char* Bg = qb + (size_t)bx * 128 * K;

  // staging: tile is 128 rows x 64 bytes = 8192 B -> 2 rounds of 256 lanes x 16 B.
  // LDS slot idx holds global chunk (idx&3) ^ (row&3) of row idx>>2.
  const int idx0 = t, idx1 = t + 256;
  const int r0 = idx0 >> 2, r1 = idx1 >> 2;
  const int g0 = (idx0 & 3) ^ (r0 & 3);
  const int g1 = (idx1 & 3) ^ (r1 & 3);
  const size_t a_off0 = (size_t)r0 * K + (size_t)g0 * 16;
  const size_t a_off1 = (size_t)r1 * K + (size_t)g1 * 16;

  // fragment-read swizzle components
  const int rsw = lrow & 3;            // row&3 for all rows this lane reads
  const int csel = lq >> 1;            // which 16B chunk within the 32B k-step
  const int ebyte = (lq & 1) << 3;     // 8B half within the chunk

  f32x4 acc[4][4];
#pragma unroll
  for (int i = 0; i < 4; i++)
#pragma unroll
    for (int j = 0; j < 4; j++) acc[i][j] = (f32x4){0.f, 0.f, 0.f, 0.f};

  for (int kt = 0; kt < K; kt += 64) {
    async_load16(Ag + a_off0 + kt, lds_a + idx0 * 16);
    async_load16(Ag + a_off1 + kt, lds_a + idx1 * 16);
    async_load16(Bg + a_off0 + kt, lds_b + idx0 * 16);
    async_load16(Bg + a_off1 + kt, lds_b + idx1 * 16);
    __syncthreads();  // compiler emits vmcnt(0) drain before s_barrier

#pragma unroll
    for (int s = 0; s < 2; s++) {
      const int coff = (((s * 2 + csel) ^ rsw) << 4) | ebyte;
      long af[4], bf[4];
#pragma unroll
      for (int i = 0; i < 4; i++)
        af[i] = *(const long*)(lds_a + (wm * 64 + i * 16 + lrow) * 64 + coff);
#pragma unroll
      for (int j = 0; j < 4; j++)
        bf[j] = *(const long*)(lds_b + (wn * 64 + j * 16 + lrow) * 64 + coff);
#pragma unroll
      for (int i = 0; i < 4; i++)
#pragma unroll
        for (int j = 0; j < 4; j++)
          acc[i][j] = __builtin_amdgcn_mfma_f32_16x16x32_fp8_fp8(af[i], bf[j], acc[i][j], 0, 0, 0);
    }
    __syncthreads();
  }

  const float s_comb =
      (fmaxf(__uint_as_float(*amax_bits), 1e-12f) / 448.0f) * wscale[0];
  const int m_base = by * 128 + wm * 64;
  const int n_base = bx * 128 + wn * 64;
#pragma unroll
  for (int j = 0; j < 4; j++) {
    const int col = n_base + j * 16 + lrow;
    const float bv = bias[col];
#pragma unroll
    for (int i = 0; i < 4; i++) {
      const int row0 = m_base + i * 16 + lq * 4;
      float* po = out + (size_t)row0 * N + col;
#pragma unroll
      for (int r = 0; r < 4; r++)
        po[(size_t)r * N] = acc[i][j][r] * s_comb + bv;
    }
  }
}

// ---------- launch ----------

extern "C" void kernel_launch(void* const* d_in, const int* in_sizes, int n_in,
                              void* d_out, int out_size, void* d_ws, size_t ws_size,
                              hipStream_t stream) {
  const float* x = (const float*)d_in[0];        // [B,S,K] fp32
  const float* qw = (const float*)d_in[1];       // [N,K] fp32 (pre-scaled fp8 values)
  const float* wscale = (const float*)d_in[2];   // [1] fp32
  const float* bias = (const float*)d_in[3];     // [N] fp32

  const int N = in_sizes[3];
  const int K = in_sizes[1] / N;
  const int M = in_sizes[0] / K;

  const long nx = (long)M * K;
  const long nw = (long)N * K;

  unsigned char* ws = (unsigned char*)d_ws;
  unsigned* amax_bits = (unsigned*)ws;
  unsigned char* qx8 = ws + 256;
  unsigned char* qw8 = qx8 + nx;

  float* out = (float*)d_out;

  hipMemsetAsync(d_ws, 0, 4, stream);
  k_amax<<<2048, 256, 0, stream>>>((const float4*)x, nx / 4, amax_bits);
  k_quant_x<<<(int)(nx / (256 * 16)), 256, 0, stream>>>((const float4*)x, (uint4*)qx8, amax_bits);
  k_quant_w<<<(int)(nw / (256 * 16)), 256, 0, stream>>>((const float4*)qw, (uint4*)qw8);
  dim3 grid(N / 128, M / 128);
  k_gemm<<<grid, 256, 0, stream>>>(qx8, qw8, amax_bits, wscale, bias, out, M, N, K);
}

// Round 3
// 446.505 us; speedup vs baseline: 1.7749x; 1.4090x over previous
//
#include <hip/hip_runtime.h>
#include <stdint.h>

#define FP8_MAX 448.0f

typedef float f32x16 __attribute__((ext_vector_type(16)));
typedef int i32x8 __attribute__((ext_vector_type(8)));

// ---------- helpers ----------

// async global->LDS, 16B per lane. LDS dest must be wave-uniform base + lane*16.
__device__ __forceinline__ void async_load16(const void* gptr, void* lptr) {
  __builtin_amdgcn_global_load_lds(
      (const __attribute__((address_space(1))) unsigned int*)(uintptr_t)gptr,
      (__attribute__((address_space(3))) unsigned int*)(unsigned)(uintptr_t)lptr,
      16, 0, 0);
}

// pack 4 fp32 -> 4 fp8 e4m3fn bytes (RNE, OCP on gfx950), byte0 = a
__device__ __forceinline__ unsigned pack4_fp8(float a, float b, float c, float d) {
  int v = __builtin_amdgcn_cvt_pk_fp8_f32(a, b, 0, false);
  v = __builtin_amdgcn_cvt_pk_fp8_f32(c, d, v, true);
  return (unsigned)v;
}

__device__ __forceinline__ float clip_fp8(float q) {
  return fminf(FP8_MAX, fmaxf(-FP8_MAX, q));
}

// assemble a 32-byte A/B fragment from two 16B LDS chunks
__device__ __forceinline__ i32x8 frag32(const unsigned char* rowbase, int o_lo, int o_hi) {
  uint4 lo = *(const uint4*)(rowbase + o_lo);
  uint4 hi = *(const uint4*)(rowbase + o_hi);
  i32x8 f;
  f[0] = lo.x; f[1] = lo.y; f[2] = lo.z; f[3] = lo.w;
  f[4] = hi.x; f[5] = hi.y; f[6] = hi.z; f[7] = hi.w;
  return f;
}

// ---------- pass 1: amax reduction ----------

__global__ void k_amax(const float4* __restrict__ x, long n4, unsigned* __restrict__ out) {
  float m = 0.f;
  const long stride = (long)gridDim.x * blockDim.x;
  for (long i = (long)blockIdx.x * blockDim.x + threadIdx.x; i < n4; i += stride) {
    float4 v = x[i];
    m = fmaxf(m, fmaxf(fmaxf(fabsf(v.x), fabsf(v.y)), fmaxf(fabsf(v.z), fabsf(v.w))));
  }
#pragma unroll
  for (int off = 32; off > 0; off >>= 1)
    m = fmaxf(m, __shfl_xor(m, off, 64));
  __shared__ float sm[4];
  const int wv = threadIdx.x >> 6;
  if ((threadIdx.x & 63) == 0) sm[wv] = m;
  __syncthreads();
  if (threadIdx.x == 0) {
    m = fmaxf(fmaxf(sm[0], sm[1]), fmaxf(sm[2], sm[3]));
    // all values >= 0: uint bit-pattern order == float order
    atomicMax(out, __float_as_uint(m));
  }
}

// ---------- pass 2: quantize x. Unit-stride float4 loads, unit-stride u32 stores ----------

__global__ void k_quant_x(const float4* __restrict__ x, unsigned* __restrict__ q,
                          const unsigned* __restrict__ amax_bits) {
  const float scale = fmaxf(__uint_as_float(*amax_bits), 1e-12f) / 448.0f;
  const long i0 = (long)blockIdx.x * blockDim.x + threadIdx.x;
  const long stride = (long)gridDim.x * blockDim.x;
#pragma unroll
  for (int r = 0; r < 4; r++) {
    const long i = i0 + r * stride;
    float4 v = x[i];
    // true IEEE division to match reference rounding
    q[i] = pack4_fp8(clip_fp8(v.x / scale), clip_fp8(v.y / scale),
                     clip_fp8(v.z / scale), clip_fp8(v.w / scale));
  }
}

// ---------- pass 3: quantize weight (values pre-scaled; just clip+RNE->fp8) ----------

__global__ void k_quant_w(const float4* __restrict__ w, unsigned* __restrict__ q) {
  const long i0 = (long)blockIdx.x * blockDim.x + threadIdx.x;
  const long stride = (long)gridDim.x * blockDim.x;
#pragma unroll
  for (int r = 0; r < 4; r++) {
    const long i = i0 + r * stride;
    float4 v = w[i];
    q[i] = pack4_fp8(clip_fp8(v.x), clip_fp8(v.y), clip_fp8(v.z), clip_fp8(v.w));
  }
}

// ---------- pass 4: fp8 GEMM via MX-scaled MFMA (unit scales) ----------
// Block tile 128(m) x 256(n), BK=64. 4 waves in 2x2; wave tile 64x128 =
// 2x4 of 32x32x64 mfma_scale_f32_32x32x64_f8f6f4 (cbsz=blgp=0 -> fp8 e4m3,
// scale bytes 0x7f = 2^0 -> numerically plain fp8 GEMM at 2x the rate).
//
// LDS swizzle: 16B chunk g of row r lives at slot g ^ ((r>>1)&3). Applied on
// the GLOBAL source address during global_load_lds (lane->LDS stays
// contiguous as HW requires) and on LDS addresses during fragment reads.
// For b128 fragment reads this gives 8 lanes per bank-quad = the 8-cycle
// floor for a 1024B wave read.
//
// A-frag layout (32x32x64): m = lane&31, k = 32*(lane>>5) + byte_idx.
// C/D layout (32x32, shape-determined): col = lane&31,
//   row = (reg&3) + 8*(reg>>2) + 4*(lane>>5).

__global__ __launch_bounds__(256, 2) void k_gemm(
    const unsigned char* __restrict__ qa, const unsigned char* __restrict__ qb,
    const unsigned* __restrict__ amax_bits, const float* __restrict__ wscale,
    const float* __restrict__ bias, float* __restrict__ out,
    int M, int N, int K) {
  __shared__ unsigned char lds_a[128 * 64];   // 8 KB
  __shared__ unsigned char lds_b[256 * 64];   // 16 KB

  const int t = threadIdx.x;
  const int lane = t & 63;
  const int wv = t >> 6;
  const int wm = wv >> 1, wn = wv & 1;   // 2x2 wave grid; wave tile 64(m) x 128(n)
  const int lr = lane & 31;              // row within 32-block
  const int h = lane >> 5;               // K-half selector

  const int bx = blockIdx.x;  // n tile (256 wide)
  const int by = blockIdx.y;  // m tile (128 tall)

  const unsigned char* Ag = qa + (size_t)by * 128 * K;
  const unsigned char* Bg = qb + (size_t)bx * 256 * K;

  // staging offsets: A = 512 chunks (2 rounds), B = 1024 chunks (4 rounds)
  size_t a_goff[2]; int a_doff[2];
#pragma unroll
  for (int r = 0; r < 2; r++) {
    const int idx = t + r * 256;
    const int row = idx >> 2;
    const int ch = (idx & 3) ^ ((row >> 1) & 3);
    a_goff[r] = (size_t)row * K + (size_t)ch * 16;
    a_doff[r] = idx * 16;
  }
  size_t b_goff[4]; int b_doff[4];
#pragma unroll
  for (int r = 0; r < 4; r++) {
    const int idx = t + r * 256;
    const int row = idx >> 2;
    const int ch = (idx & 3) ^ ((row >> 1) & 3);
    b_goff[r] = (size_t)row * K + (size_t)ch * 16;
    b_doff[r] = idx * 16;
  }

  // fragment-read addresses (swizzled chunk offsets for this lane's rows;
  // row bases are multiples of 32 so (row>>1)&3 == (lr>>1)&3)
  const int g = (lr >> 1) & 3;
  const int c_lo = ((2 * h + 0) ^ g) * 16;
  const int c_hi = ((2 * h + 1) ^ g) * 16;
  int arow[2], brow[4];
#pragma unroll
  for (int i = 0; i < 2; i++) arow[i] = (wm * 64 + i * 32 + lr) * 64;
#pragma unroll
  for (int j = 0; j < 4; j++) brow[j] = (wn * 128 + j * 32 + lr) * 64;

  f32x16 acc[2][4];
#pragma unroll
  for (int i = 0; i < 2; i++)
#pragma unroll
    for (int j = 0; j < 4; j++)
#pragma unroll
      for (int r = 0; r < 16; r++) acc[i][j][r] = 0.f;

  for (int kt = 0; kt < K; kt += 64) {
#pragma unroll
    for (int r = 0; r < 2; r++) async_load16(Ag + a_goff[r] + kt, lds_a + a_doff[r]);
#pragma unroll
    for (int r = 0; r < 4; r++) async_load16(Bg + b_goff[r] + kt, lds_b + b_doff[r]);
    __syncthreads();

    i32x8 af[2], bf[4];
#pragma unroll
    for (int i = 0; i < 2; i++) af[i] = frag32(lds_a + arow[i], c_lo, c_hi);
#pragma unroll
    for (int j = 0; j < 4; j++) bf[j] = frag32(lds_b + brow[j], c_lo, c_hi);

#pragma unroll
    for (int i = 0; i < 2; i++)
#pragma unroll
      for (int j = 0; j < 4; j++)
        acc[i][j] = __builtin_amdgcn_mfma_scale_f32_32x32x64_f8f6f4(
            af[i], bf[j], acc[i][j], 0, 0, 0, 0x7f7f7f7f, 0, 0x7f7f7f7f);
    __syncthreads();
  }

  const float s_comb =
      (fmaxf(__uint_as_float(*amax_bits), 1e-12f) / 448.0f) * wscale[0];
  const int m_base = by * 128 + wm * 64;
  const int n_base = bx * 256 + wn * 128;
#pragma unroll
  for (int j = 0; j < 4; j++) {
    const int col = n_base + j * 32 + lr;
    const float bv = bias[col];
#pragma unroll
    for (int i = 0; i < 2; i++) {
      const int row0 = m_base + i * 32 + 4 * h;
#pragma unroll
      for (int r = 0; r < 16; r++) {
        const int row = row0 + (r & 3) + 8 * (r >> 2);
        out[(size_t)row * N + col] = acc[i][j][r] * s_comb + bv;
      }
    }
  }
}

// ---------- launch ----------

extern "C" void kernel_launch(void* const* d_in, const int* in_sizes, int n_in,
                              void* d_out, int out_size, void* d_ws, size_t ws_size,
                              hipStream_t stream) {
  const float* x = (const float*)d_in[0];        // [B,S,K] fp32
  const float* qw = (const float*)d_in[1];       // [N,K] fp32 (pre-scaled fp8 values)
  const float* wscale = (const float*)d_in[2];   // [1] fp32
  const float* bias = (const float*)d_in[3];     // [N] fp32

  const int N = in_sizes[3];
  const int K = in_sizes[1] / N;
  const int M = in_sizes[0] / K;

  const long nx = (long)M * K;
  const long nw = (long)N * K;

  unsigned char* ws = (unsigned char*)d_ws;
  unsigned* amax_bits = (unsigned*)ws;
  unsigned char* qx8 = ws + 256;
  unsigned char* qw8 = qx8 + nx;

  float* out = (float*)d_out;

  hipMemsetAsync(d_ws, 0, 4, stream);
  k_amax<<<2048, 256, 0, stream>>>((const float4*)x, nx / 4, amax_bits);
  // each thread handles 4 float4s, unit-stride within each pass
  k_quant_x<<<(int)(nx / 4 / 4 / 256), 256, 0, stream>>>(
      (const float4*)x, (unsigned*)qx8, amax_bits);
  k_quant_w<<<(int)(nw / 4 / 4 / 256), 256, 0, stream>>>(
      (const float4*)qw, (unsigned*)qw8);
  dim3 grid(N / 256, M / 128);
  k_gemm<<<grid, 256, 0, stream>>>(qx8, qw8, amax_bits, wscale, bias, out, M, N, K);
}